// Round 2
// baseline (131.573 us; speedup 1.0000x reference)
//
#include <hip/hip_runtime.h>
#include <hip/hip_bf16.h>

// Mathematical collapse of the reference:
//   tr = (op - op) * weight == 0 exactly for finite op  (the reference is
//   explicitly "faithful to the source, which computes A - A").
//   => real_sum == 0
//   => z1 = relu(bf1); z2 = relu(Wf2 @ z1 + bf2);
//      out[b] = Wf3 . z2 + bf3   (same scalar for every batch row b).
// All other inputs (embeddings, LSTM, MLPs, phases, Wf1) are dead w.r.t. d_out.
//
// Dtype note (round-1 post-mortem): all tensors are float32. Reading them as
// bf16 produced NaNs (low halves of f32 mantissas decode to NaN w.p. ~1/256).

#define PF 128
#define BOUT 32  // B * OUT = 32 * 1

__global__ __launch_bounds__(PF) void TF2N_35347580846484_kernel(
    const float* __restrict__ bf1,   // (128,)
    const float* __restrict__ Wf2,   // (128,128) row-major
    const float* __restrict__ bf2,   // (128,)
    const float* __restrict__ Wf3,   // (1,128)
    const float* __restrict__ bf3,   // (1,)
    float* __restrict__ out)         // (32,)
{
    __shared__ float z1[PF];
    __shared__ float z2[PF];
    const int tid = threadIdx.x;

    // z1 = relu(bf1)
    float v = bf1[tid];
    z1[tid] = v > 0.f ? v : 0.f;
    __syncthreads();

    // z2 = relu(Wf2 @ z1 + bf2)  — one row per thread
    float acc = bf2[tid];
    const float* row = Wf2 + tid * PF;
#pragma unroll 8
    for (int j = 0; j < PF; ++j)
        acc = fmaf(row[j], z1[j], acc);
    z2[tid] = acc > 0.f ? acc : 0.f;
    __syncthreads();

    // out = Wf3 . z2 + bf3, broadcast to all 32 batch rows.
    // Tiny final dot; whole kernel is launch-latency bound anyway.
    if (tid == 0) {
        float s = bf3[0];
        for (int j = 0; j < PF; ++j)
            s = fmaf(Wf3[j], z2[j], s);
        for (int b = 0; b < BOUT; ++b) out[b] = s;
    }
}

extern "C" void kernel_launch(void* const* d_in, const int* in_sizes, int n_in,
                              void* d_out, int out_size, void* d_ws, size_t ws_size,
                              hipStream_t stream) {
    // setup_inputs() dict order:
    //  0 word_indexes  1 video  2 audio  3 embed_E  4 phase0  5 phase1  6 phase2
    //  7 W_ih  8 W_hh  9 b_ih 10 b_hh 11 Wt 12 bt
    // 13 Wv1 14 bv1 15 Wv2 16 bv2 17 Wv3 18 bv3
    // 19 Wa1 20 ba1 21 Wa2 22 ba2 23 Wa3 24 ba3
    // 25 mod_w 26 Wf1 27 bf1 28 Wf2 29 bf2 30 Wf3 31 bf3
    const float* bf1 = (const float*)d_in[27];
    const float* Wf2 = (const float*)d_in[28];
    const float* bf2 = (const float*)d_in[29];
    const float* Wf3 = (const float*)d_in[30];
    const float* bf3 = (const float*)d_in[31];
    float* out = (float*)d_out;

    TF2N_35347580846484_kernel<<<1, PF, 0, stream>>>(bf1, Wf2, bf2, Wf3, bf3, out);
}